// Round 13
// baseline (979.322 us; speedup 1.0000x reference)
//
#include <hip/hip_runtime.h>

// ---------------------------------------------------------------------------
// LSTM forecaster. R13 = R12 +
//  (1) feedback folding: y@dWih0^T == h1@(dWih0*headW)^T + dWih0*headB
//      -> Wd0c = [dWhh0 | Wcomb] (512x256, 512B rows, reuses eo1 offsets),
//      bias fold into bsT set2. Decoder: ybuf + barrier A GONE (2 barriers).
//      Skip Wcomb half at t=0 (reference y0 = 0).
//  (2) head spread over all 512 threads (4-way split dots; partials pre-B,
//      leader sum+store post-B) -> off the critical path.
//  (3) kk-round stagger kk=(kk0+bid)&3 per mma4: de-phases XCD-wide
//      same-line weight bursts at L2 (numerically exact).
// Structure: 256 blocks x 64 batch, 8 waves, 4m x 4n, c-state in LDS,
// encoder layer-pipelined (1 barrier/window). V-half rule: waves/SIMD =
// 256/VGPR -> pinned at 2 waves/SIMD; latency must be cut in-wave.
// ---------------------------------------------------------------------------

typedef __attribute__((ext_vector_type(8))) short short8;   // 8 x bf16 frag
typedef __attribute__((ext_vector_type(4))) float float4v;  // 4 x f32 acc

#define MFMA16(a, b, c) __builtin_amdgcn_mfma_f32_16x16x32_bf16((a), (b), (c), 0, 0, 0)

__device__ __forceinline__ unsigned short f2bf(float x) {
    unsigned u = __builtin_bit_cast(unsigned, x);
    unsigned r = (u + 0x7FFFu + ((u >> 16) & 1u)) >> 16;  // RNE
    return (unsigned short)r;
}
__device__ __forceinline__ float bf2f(unsigned short b) {
    unsigned u = ((unsigned)b) << 16;
    return __builtin_bit_cast(float, u);
}

#if __has_builtin(__builtin_amdgcn_exp2f)
__device__ __forceinline__ float vexp2(float x) { return __builtin_amdgcn_exp2f(x); }
#else
__device__ __forceinline__ float vexp2(float x) { return exp2f(x); }
#endif
#if __has_builtin(__builtin_amdgcn_rcpf)
__device__ __forceinline__ float vrcp(float x) { return __builtin_amdgcn_rcpf(x); }
#else
__device__ __forceinline__ float vrcp(float x) { return 1.0f / x; }
#endif

__device__ __forceinline__ float sigm(float x) {
    return vrcp(1.0f + vexp2(x * -1.442695040888963f));
}
__device__ __forceinline__ float tanh_(float x) {
    return 1.0f - 2.0f * vrcp(1.0f + vexp2(x * 2.885390081777927f));
}

// ---------------------------------------------------------------------------
// prep: fp32 -> bf16 weights. ws layout (bytes):
//   We0 [512][160]  @ 0       (163840)
//   We1 [512][256]  @ 163840  (262144)
//   Wd0c[512][256]  @ 425984  (262144)  rows = [dWhh0 | Wcomb], Wcomb = dWih0*headW
//   Wd1 [512][256]  @ 688128  (262144)
//   bsT [4][128][4] @ 950272  (8192, f32) set2 += dWih0*headB
// ---------------------------------------------------------------------------
__global__ void prep_kernel(const float* __restrict__ eWih0, const float* __restrict__ eWhh0,
                            const float* __restrict__ ebih0, const float* __restrict__ ebhh0,
                            const float* __restrict__ eWih1, const float* __restrict__ eWhh1,
                            const float* __restrict__ ebih1, const float* __restrict__ ebhh1,
                            const float* __restrict__ dWih0, const float* __restrict__ dWhh0,
                            const float* __restrict__ dbih0, const float* __restrict__ dbhh0,
                            const float* __restrict__ dWih1, const float* __restrict__ dWhh1,
                            const float* __restrict__ dbih1, const float* __restrict__ dbhh1,
                            const float* __restrict__ headW, const float* __restrict__ headB,
                            void* __restrict__ ws)
{
    int i = blockIdx.x * 256 + threadIdx.x;
    short* We0  = (short*)ws;
    short* We1  = We0 + 512 * 160;
    short* Wd0c = We1 + 512 * 256;
    short* Wd1  = Wd0c + 512 * 256;
    float* bsT  = (float*)((char*)ws + 950272);
    const int N0 = 512 * 160, N1 = 512 * 256, N2 = 512 * 256, N3 = 512 * 256;
    if (i < N0) {
        int n = i / 160, k = i - n * 160;
        float v = (k < 32) ? (k < 10 ? eWih0[n * 10 + k] : 0.0f) : eWhh0[n * 128 + (k - 32)];
        We0[i] = (short)f2bf(v);
    } else if (i < N0 + N1) {
        int ii = i - N0, n = ii >> 8, k = ii & 255;
        float v = (k < 128) ? eWih1[n * 128 + k] : eWhh1[n * 128 + (k - 128)];
        We1[ii] = (short)f2bf(v);
    } else if (i < N0 + N1 + N2) {
        int ii = i - (N0 + N1), n = ii >> 8, k = ii & 255;
        float v = (k < 128) ? dWhh0[n * 128 + k]
                : dWih0[n * 2 + 0] * headW[(k - 128)]
                + dWih0[n * 2 + 1] * headW[128 + (k - 128)];
        Wd0c[ii] = (short)f2bf(v);
    } else if (i < N0 + N1 + N2 + N3) {
        int ii = i - (N0 + N1 + N2), n = ii >> 8, k = ii & 255;
        float v = (k < 128) ? dWih1[n * 128 + k] : dWhh1[n * 128 + (k - 128)];
        Wd1[ii] = (short)f2bf(v);
    } else if (i < N0 + N1 + N2 + N3 + 2048) {
        int ii = i - (N0 + N1 + N2 + N3);
        int set = ii >> 9, r = ii & 511, j = r >> 2, q = r & 3;
        int g = q * 128 + j;
        float v;
        if (set == 0)      v = ebih0[g] + ebhh0[g];
        else if (set == 1) v = ebih1[g] + ebhh1[g];
        else if (set == 2) v = dbih0[g] + dbhh0[g]
                             + dWih0[g * 2 + 0] * headB[0]
                             + dWih0[g * 2 + 1] * headB[1];
        else               v = dbih1[g] + dbhh1[g];
        bsT[ii] = v;
    }
}

// ---------------------------------------------------------------------------
// main kernel (per block: 64 batch rows, 8 waves)
// LDS h-buffers ping-pong [2] x (64 x 16 chunks): slot = m*16+(kc^(m&15))
// xbuf ping-pong [2] x (64 x 4 chunks): slot = m*4+(kc^(m&3))
// c-state in LDS: cbuf[m*132 + j] (2-way bank = free)
// Wave w: m-tiles {0..3}, n-tiles {w, w+8, w+16, w+24} (q = gate i/f/g/o)
// ---------------------------------------------------------------------------

template <int NKT>
__device__ __forceinline__ void mma4(float4v acc[4][4], const short8* __restrict__ hb,
                                     const char* __restrict__ wb, const unsigned* wo,
                                     int woff, int nib, int quad, int rot)
{
#pragma unroll 1
    for (int kk0 = 0; kk0 < NKT; ++kk0) {
        int kk = (kk0 + rot) & (NKT - 1);  // per-block stagger, K-order per acc unchanged
        int sx = ((kk * 4 + quad) ^ nib) + nib * 16;
        short8 a0 = hb[sx];
        short8 a1 = hb[256 + sx];
        short8 a2 = hb[512 + sx];
        short8 a3 = hb[768 + sx];
        short8 b0 = *(const short8*)(wb + (wo[0] + woff + kk * 64));
        short8 b1 = *(const short8*)(wb + (wo[1] + woff + kk * 64));
        short8 b2 = *(const short8*)(wb + (wo[2] + woff + kk * 64));
        short8 b3 = *(const short8*)(wb + (wo[3] + woff + kk * 64));
        acc[0][0] = MFMA16(a0, b0, acc[0][0]);
        acc[0][1] = MFMA16(a1, b0, acc[0][1]);
        acc[0][2] = MFMA16(a2, b0, acc[0][2]);
        acc[0][3] = MFMA16(a3, b0, acc[0][3]);
        acc[1][0] = MFMA16(a0, b1, acc[1][0]);
        acc[1][1] = MFMA16(a1, b1, acc[1][1]);
        acc[1][2] = MFMA16(a2, b1, acc[1][2]);
        acc[1][3] = MFMA16(a3, b1, acc[1][3]);
        acc[2][0] = MFMA16(a0, b2, acc[2][0]);
        acc[2][1] = MFMA16(a1, b2, acc[2][1]);
        acc[2][2] = MFMA16(a2, b2, acc[2][2]);
        acc[2][3] = MFMA16(a3, b2, acc[2][3]);
        acc[3][0] = MFMA16(a0, b3, acc[3][0]);
        acc[3][1] = MFMA16(a1, b3, acc[3][1]);
        acc[3][2] = MFMA16(a2, b3, acc[3][2]);
        acc[3][3] = MFMA16(a3, b3, acc[3][3]);
    }
}

// elementwise LSTM cell update; c-state in LDS (cbase), h (bf16) to hdst
__device__ __forceinline__ void cell_update4(float4v acc[4][4], float4v bv,
                                             float* __restrict__ cbase,
                                             unsigned short* __restrict__ hdst,
                                             int j, int quad)
{
    int kc = j >> 3;
    int jl = j & 7;
#pragma unroll
    for (int mt = 0; mt < 4; ++mt) {
#pragma unroll
        for (int r = 0; r < 4; ++r) {
            float gi = acc[0][mt][r] + bv[0];
            float gf = acc[1][mt][r] + bv[1];
            float gg = acc[2][mt][r] + bv[2];
            float go = acc[3][mt][r] + bv[3];
            int m = mt * 16 + quad * 4 + r;
            float si = sigm(gi);
            float sf = sigm(gf);
            float tg = tanh_(gg);
            float so = sigm(go);
            float* cp = cbase + (m * 132 + j);
            float c = sf * (*cp) + si * tg;
            *cp = c;
            float h = so * tanh_(c);
            int slot = m * 16 + (kc ^ (m & 15));
            hdst[slot * 8 + jl] = f2bf(h);
        }
    }
}

__global__ void __attribute__((amdgpu_flat_work_group_size(512, 512), amdgpu_waves_per_eu(2)))
lstm_main(
    const float* __restrict__ hist,
    const float* __restrict__ headW, const float* __restrict__ headB,
    const int* __restrict__ futlen, const void* __restrict__ ws,
    float* __restrict__ out)
{
    __shared__ short8 h0buf[2][1024];  // ping-pong, 64 x 16 chunks (32 KB)
    __shared__ short8 h1buf[2][1024];  // 32 KB
    __shared__ short8 xbuf[2][256];    // ping-pong, 64 x 4 chunks (8 KB)
    __shared__ float hpart[512];       // head partial dots (2 KB)
    __shared__ float cbuf0[64 * 132];  // c-state layer 0 (33 KB)
    __shared__ float cbuf1[64 * 132];  // c-state layer 1 (33 KB)

    const char* wsb  = (const char*)ws;
    const char* We0  = wsb;                  // rows of 320 B
    const char* We1  = wsb + 163840;         // rows of 512 B
    const char* Wd0c = wsb + 425984;         // rows of 512 B: [dWhh0 | Wcomb]
    const char* Wd1  = wsb + 688128;         // rows of 512 B
    const float* bsT = (const float*)(wsb + 950272);

    const int tid = threadIdx.x;
    const int w = tid >> 6;
    const int lane = tid & 63;
    const int quad = lane >> 4;
    const int nib = lane & 15;
    const int b0 = blockIdx.x * 64;
    const int TFUT = *futlen;
    const int j = 16 * w + nib;
    const int rotk = blockIdx.x & 3;

    // zero-init LDS state. h1: both parities (pipelined L1(0) reads h1[1]).
    // xbuf: both parities, all chunks (chunks 2-3 = permanent K=32 padding).
    h0buf[0][tid] = (short8)0;
    h0buf[0][512 + tid] = (short8)0;
    h1buf[0][tid] = (short8)0;
    h1buf[0][512 + tid] = (short8)0;
    h1buf[1][tid] = (short8)0;
    h1buf[1][512 + tid] = (short8)0;
    ((short8*)xbuf)[tid] = (short8)0;   // 512 slots = both parities
    for (int i = tid; i < 64 * 132; i += 512) {
        cbuf0[i] = 0.0f;
        cbuf1[i] = 0.0f;
    }
    __syncthreads();  // zero-init visible before initial staging writes

    // stage x(t=0) into xbuf[0]
    if (tid < 128) {
        int m = tid & 63, part = tid >> 6;
        const float* hp = hist + ((size_t)((b0 + m) * 20 + 0)) * 10;
        float v[8];
        if (part == 0) {
#pragma unroll
            for (int i = 0; i < 8; ++i) v[i] = hp[i];
        } else {
            v[0] = hp[8]; v[1] = hp[9];
#pragma unroll
            for (int i = 2; i < 8; ++i) v[i] = 0.0f;
        }
        short8 pk;
#pragma unroll
        for (int i = 0; i < 8; ++i) pk[i] = (short)f2bf(v[i]);
        xbuf[0][m * 4 + (part ^ (m & 3))] = pk;
    }

    // 32-bit B-row byte offsets: row = 16*(w+8q)+nib, + quad*16.
    // eo1 serves We1, Wd0c, Wd1 (all 512-B row stride).
    unsigned eo0[4], eo1[4];
#pragma unroll
    for (int q = 0; q < 4; ++q) {
        unsigned row = 16u * (w + 8 * q) + nib;
        eo0[q] = row * 320u + quad * 16u;
        eo1[q] = row * 512u + quad * 16u;
    }
    int p0 = 0, p1 = 0, px = 0;
    __syncthreads();

    // ================= ENCODER: 21 layer-pipelined windows =================
#pragma unroll 1
    for (int wdw = 0; wdw < 21; ++wdw) {
        if (wdw < 20) {
            // ---- L0(wdw): gates = x@Wih0^T + h0@Whh0^T; fused cell ----
            float4v acc[4][4];
#pragma unroll
            for (int q = 0; q < 4; ++q)
#pragma unroll
                for (int mt = 0; mt < 4; ++mt) acc[q][mt] = (float4v){0.f, 0.f, 0.f, 0.f};
            {
                const short8* xb = xbuf[px];
                int sxx = (quad ^ (nib & 3)) + nib * 4;
                short8 a0 = xb[sxx];
                short8 a1 = xb[64 + sxx];
                short8 a2 = xb[128 + sxx];
                short8 a3 = xb[192 + sxx];
                short8 bq0 = *(const short8*)(We0 + eo0[0]);
                short8 bq1 = *(const short8*)(We0 + eo0[1]);
                short8 bq2 = *(const short8*)(We0 + eo0[2]);
                short8 bq3 = *(const short8*)(We0 + eo0[3]);
                acc[0][0] = MFMA16(a0, bq0, acc[0][0]);
                acc[0][1] = MFMA16(a1, bq0, acc[0][1]);
                acc[0][2] = MFMA16(a2, bq0, acc[0][2]);
                acc[0][3] = MFMA16(a3, bq0, acc[0][3]);
                acc[1][0] = MFMA16(a0, bq1, acc[1][0]);
                acc[1][1] = MFMA16(a1, bq1, acc[1][1]);
                acc[1][2] = MFMA16(a2, bq1, acc[1][2]);
                acc[1][3] = MFMA16(a3, bq1, acc[1][3]);
                acc[2][0] = MFMA16(a0, bq2, acc[2][0]);
                acc[2][1] = MFMA16(a1, bq2, acc[2][1]);
                acc[2][2] = MFMA16(a2, bq2, acc[2][2]);
                acc[2][3] = MFMA16(a3, bq2, acc[2][3]);
                acc[3][0] = MFMA16(a0, bq3, acc[3][0]);
                acc[3][1] = MFMA16(a1, bq3, acc[3][1]);
                acc[3][2] = MFMA16(a2, bq3, acc[3][2]);
                acc[3][3] = MFMA16(a3, bq3, acc[3][3]);
            }
            mma4<4>(acc, h0buf[p0], We0, eo0, 64, nib, quad, rotk);
            float4v bv = *(const float4v*)(bsT + 0 * 512 + j * 4);
            cell_update4(acc, bv, cbuf0, (unsigned short*)h0buf[p0 ^ 1], j, quad);
        }

        // stage x(wdw+1) into xbuf[px^1]
        if (tid < 128 && wdw < 19) {
            int m = tid & 63, part = tid >> 6;
            const float* hp = hist + ((size_t)((b0 + m) * 20 + (wdw + 1))) * 10;
            float v[8];
            if (part == 0) {
#pragma unroll
                for (int i = 0; i < 8; ++i) v[i] = hp[i];
            } else {
                v[0] = hp[8]; v[1] = hp[9];
#pragma unroll
                for (int i = 2; i < 8; ++i) v[i] = 0.0f;
            }
            short8 pk;
#pragma unroll
            for (int i = 0; i < 8; ++i) pk[i] = (short)f2bf(v[i]);
            xbuf[px ^ 1][m * 4 + (part ^ (m & 3))] = pk;
        }

        if (wdw >= 1) {
            // ---- L1(wdw-1): gates = h0(wdw-1)@Wih1^T + h1(wdw-2)@Whh1^T ----
            float4v acc[4][4];
#pragma unroll
            for (int q = 0; q < 4; ++q)
#pragma unroll
                for (int mt = 0; mt < 4; ++mt) acc[q][mt] = (float4v){0.f, 0.f, 0.f, 0.f};
            mma4<4>(acc, h0buf[p0], We1, eo1, 0, nib, quad, rotk);   // pre-window h0
            mma4<4>(acc, h1buf[p1], We1, eo1, 256, nib, quad, rotk);
            float4v bv = *(const float4v*)(bsT + 1 * 512 + j * 4);
            cell_update4(acc, bv, cbuf1, (unsigned short*)h1buf[p1 ^ 1], j, quad);
        }
        __syncthreads();
        p0 ^= 1; p1 ^= 1; px ^= 1;
    }

    // Parity ledger: h0(19) -> h0[0]; h1(19) -> h1[1].
    p0 = 0;
    p1 = 1;

    // ================= DECODER: 2 barriers/step =================
    // window t: [head-partials(t-1) all 512 thr] ; mma0(t)=h0@Wd0 (+h1@Wcomb
    // if t>0) ; cell0 ; B ; [leader sum+store(t-1) || mma1(t)] ; cell1 ; C.
#pragma unroll 1
    for (int t = 0; t < TFUT; ++t) {
        // head partial dots for y(t-1): thread -> (pair=tid>>2, qh=tid&3)
        if (t >= 1) {
            int pair = tid >> 2, qh = tid & 3;
            int m = pair >> 1, jj = pair & 1;
            const short8* hb = h1buf[p1];
            const float4v* hw = (const float4v*)(headW + jj * 128);
            int mk = m & 15;
            float dot = 0.0f;
#pragma unroll
            for (int kq = 0; kq < 4; ++kq) {
                int kc = qh * 4 + kq;
                short8 ch = hb[m * 16 + (kc ^ mk)];
                float4v w0 = hw[kc * 2], w1 = hw[kc * 2 + 1];
                dot += bf2f((unsigned short)ch[0]) * w0[0];
                dot += bf2f((unsigned short)ch[1]) * w0[1];
                dot += bf2f((unsigned short)ch[2]) * w0[2];
                dot += bf2f((unsigned short)ch[3]) * w0[3];
                dot += bf2f((unsigned short)ch[4]) * w1[0];
                dot += bf2f((unsigned short)ch[5]) * w1[1];
                dot += bf2f((unsigned short)ch[6]) * w1[2];
                dot += bf2f((unsigned short)ch[7]) * w1[3];
            }
            hpart[tid] = dot;
        }

        // ---- dec layer 0: gates = h0@dWhh0^T + h1@Wcomb^T (+bias fold) ----
        {
            float4v acc[4][4];
#pragma unroll
            for (int q = 0; q < 4; ++q)
#pragma unroll
                for (int mt = 0; mt < 4; ++mt) acc[q][mt] = (float4v){0.f, 0.f, 0.f, 0.f};
            mma4<4>(acc, h0buf[p0], Wd0c, eo1, 0, nib, quad, rotk);
            if (t > 0)
                mma4<4>(acc, h1buf[p1], Wd0c, eo1, 256, nib, quad, rotk);
            float4v bv = *(const float4v*)(bsT + 2 * 512 + j * 4);
            cell_update4(acc, bv, cbuf0, (unsigned short*)h0buf[p0 ^ 1], j, quad);
        }
        __syncthreads();  // B: h0 new + hpart visible

        // leader sum + store y(t-1), overlapped with mma1
        if (tid < 128 && t >= 1) {
            int m = tid >> 1, jj = tid & 1;
            float dot = headB[jj] + hpart[tid * 4] + hpart[tid * 4 + 1]
                      + hpart[tid * 4 + 2] + hpart[tid * 4 + 3];
            out[((size_t)(b0 + m) * TFUT + (t - 1)) * 2 + jj] = dot;
        }

        // ---- dec layer 1 ----
        {
            float4v acc[4][4];
#pragma unroll
            for (int q = 0; q < 4; ++q)
#pragma unroll
                for (int mt = 0; mt < 4; ++mt) acc[q][mt] = (float4v){0.f, 0.f, 0.f, 0.f};
            mma4<4>(acc, h0buf[p0 ^ 1], Wd1, eo1, 0, nib, quad, rotk);
            mma4<4>(acc, h1buf[p1], Wd1, eo1, 256, nib, quad, rotk);
            float4v bv = *(const float4v*)(bsT + 3 * 512 + j * 4);
            cell_update4(acc, bv, cbuf1, (unsigned short*)h1buf[p1 ^ 1], j, quad);
        }
        __syncthreads();  // C: h1 new visible
        p0 ^= 1; p1 ^= 1;
    }

    // ---- epilogue: head(TFUT-1) ----
    {
        int pair = tid >> 2, qh = tid & 3;
        int m = pair >> 1, jj = pair & 1;
        const short8* hb = h1buf[p1];
        const float4v* hw = (const float4v*)(headW + jj * 128);
        int mk = m & 15;
        float dot = 0.0f;
#pragma unroll
        for (int kq = 0; kq < 4; ++kq) {
            int kc = qh * 4 + kq;
            short8 ch = hb[m * 16 + (kc ^ mk)];
            float4v w0 = hw[kc * 2], w1 = hw[kc * 2 + 1];
            dot += bf2f((unsigned short)ch[0]) * w0[0];
            dot += bf2f((unsigned short)ch[1]) * w0[1];
            dot += bf2f((unsigned short)ch[2]) * w0[2];
            dot += bf2f((unsigned short)ch[3]) * w0[3];
            dot += bf2f((unsigned short)ch[4]) * w1[0];
            dot += bf2f((unsigned short)ch[5]) * w1[1];
            dot += bf2f((unsigned short)ch[6]) * w1[2];
            dot += bf2f((unsigned short)ch[7]) * w1[3];
        }
        hpart[tid] = dot;
    }
    __syncthreads();
    if (tid < 128) {
        int m = tid >> 1, jj = tid & 1;
        float dot = headB[jj] + hpart[tid * 4] + hpart[tid * 4 + 1]
                  + hpart[tid * 4 + 2] + hpart[tid * 4 + 3];
        out[((size_t)(b0 + m) * TFUT + (TFUT - 1)) * 2 + jj] = dot;
    }
}

extern "C" void kernel_launch(void* const* d_in, const int* in_sizes, int n_in,
                              void* d_out, int out_size, void* d_ws, size_t ws_size,
                              hipStream_t stream)
{
    const float* hist   = (const float*)d_in[0];
    const float* eWih0  = (const float*)d_in[1];
    const float* eWhh0  = (const float*)d_in[2];
    const float* ebih0  = (const float*)d_in[3];
    const float* ebhh0  = (const float*)d_in[4];
    const float* eWih1  = (const float*)d_in[5];
    const float* eWhh1  = (const float*)d_in[6];
    const float* ebih1  = (const float*)d_in[7];
    const float* ebhh1  = (const float*)d_in[8];
    const float* dWih0  = (const float*)d_in[9];
    const float* dWhh0  = (const float*)d_in[10];
    const float* dbih0  = (const float*)d_in[11];
    const float* dbhh0  = (const float*)d_in[12];
    const float* dWih1  = (const float*)d_in[13];
    const float* dWhh1  = (const float*)d_in[14];
    const float* dbih1  = (const float*)d_in[15];
    const float* dbhh1  = (const float*)d_in[16];
    const float* headW  = (const float*)d_in[17];
    const float* headB  = (const float*)d_in[18];
    const int*   futlen = (const int*)d_in[19];

    // work items: 81920 + 131072 + 131072 + 131072 + 2048 = 477184 = 1864*256
    prep_kernel<<<1864, 256, 0, stream>>>(eWih0, eWhh0, ebih0, ebhh0,
                                          eWih1, eWhh1, ebih1, ebhh1,
                                          dWih0, dWhh0, dbih0, dbhh0,
                                          dWih1, dWhh1, dbih1, dbhh1,
                                          headW, headB, d_ws);

    lstm_main<<<256, 512, 0, stream>>>(hist, headW, headB, futlen,
                                       d_ws, (float*)d_out);
}

// Round 14
// 861.330 us; speedup vs baseline: 1.1370x; 1.1370x over previous
//
#include <hip/hip_runtime.h>

// ---------------------------------------------------------------------------
// LSTM forecaster. R14 = R12 (best: 871us) + depth-2 prefetch of HALF the
// B-frags (b0/b1 carried one kk-round ahead; b2/b3 fresh). 6 frags live =
// 24 regs (R10's full 8-frag prefetch = 32 regs -> spilled). VGPR 116->~124.
// R13 fully reverted: its Wcomb folding added +19% kk rounds and dur scaled
// with rounds (871->979) — per-round L2 latency is the cost unit.
// Structure: 256 blocks x 64 batch, 8 waves, 4m x 4n, c-state in LDS,
// encoder layer-pipelined (1 barrier/window), decoder head hoisted.
// ---------------------------------------------------------------------------

typedef __attribute__((ext_vector_type(8))) short short8;   // 8 x bf16 frag
typedef __attribute__((ext_vector_type(4))) float float4v;  // 4 x f32 acc

#define MFMA16(a, b, c) __builtin_amdgcn_mfma_f32_16x16x32_bf16((a), (b), (c), 0, 0, 0)

__device__ __forceinline__ unsigned short f2bf(float x) {
    unsigned u = __builtin_bit_cast(unsigned, x);
    unsigned r = (u + 0x7FFFu + ((u >> 16) & 1u)) >> 16;  // RNE
    return (unsigned short)r;
}
__device__ __forceinline__ float bf2f(unsigned short b) {
    unsigned u = ((unsigned)b) << 16;
    return __builtin_bit_cast(float, u);
}

#if __has_builtin(__builtin_amdgcn_exp2f)
__device__ __forceinline__ float vexp2(float x) { return __builtin_amdgcn_exp2f(x); }
#else
__device__ __forceinline__ float vexp2(float x) { return exp2f(x); }
#endif
#if __has_builtin(__builtin_amdgcn_rcpf)
__device__ __forceinline__ float vrcp(float x) { return __builtin_amdgcn_rcpf(x); }
#else
__device__ __forceinline__ float vrcp(float x) { return 1.0f / x; }
#endif

__device__ __forceinline__ float sigm(float x) {
    return vrcp(1.0f + vexp2(x * -1.442695040888963f));
}
__device__ __forceinline__ float tanh_(float x) {
    return 1.0f - 2.0f * vrcp(1.0f + vexp2(x * 2.885390081777927f));
}

// ---------------------------------------------------------------------------
// prep kernel: fp32 weights -> bf16, concatenated per-layer [Wih | Whh],
// Wih0 padded 10->32; biases summed AND transposed to [set][j][q] float4;
// decoder-y weights transposed to [j][8].
// ws layout: We0[512][160] | We1[512][256] | Wd0[512][128] | Wd1[512][256]
//            (bf16, 819200 B) | bsT[4][128][4] f32 (8 KB) | wyT[128][8] f32 (4 KB)
// ---------------------------------------------------------------------------
__global__ void prep_kernel(const float* __restrict__ eWih0, const float* __restrict__ eWhh0,
                            const float* __restrict__ ebih0, const float* __restrict__ ebhh0,
                            const float* __restrict__ eWih1, const float* __restrict__ eWhh1,
                            const float* __restrict__ ebih1, const float* __restrict__ ebhh1,
                            const float* __restrict__ dWih0, const float* __restrict__ dWhh0,
                            const float* __restrict__ dbih0, const float* __restrict__ dbhh0,
                            const float* __restrict__ dWih1, const float* __restrict__ dWhh1,
                            const float* __restrict__ dbih1, const float* __restrict__ dbhh1,
                            void* __restrict__ ws)
{
    int i = blockIdx.x * 256 + threadIdx.x;
    short* We0 = (short*)ws;
    short* We1 = We0 + 512 * 160;
    short* Wd0 = We1 + 512 * 256;
    short* Wd1 = Wd0 + 512 * 128;
    float* bsT = (float*)((char*)ws + 819200);
    float* wyT = bsT + 2048;
    const int N0 = 512 * 160, N1 = 512 * 256, N2 = 512 * 128, N3 = 512 * 256;
    if (i < N0) {
        int n = i / 160, k = i - n * 160;
        float v = (k < 32) ? (k < 10 ? eWih0[n * 10 + k] : 0.0f) : eWhh0[n * 128 + (k - 32)];
        We0[i] = (short)f2bf(v);
    } else if (i < N0 + N1) {
        int ii = i - N0, n = ii >> 8, k = ii & 255;
        float v = (k < 128) ? eWih1[n * 128 + k] : eWhh1[n * 128 + (k - 128)];
        We1[ii] = (short)f2bf(v);
    } else if (i < N0 + N1 + N2) {
        int ii = i - (N0 + N1);
        Wd0[ii] = (short)f2bf(dWhh0[ii]);
    } else if (i < N0 + N1 + N2 + N3) {
        int ii = i - (N0 + N1 + N2), n = ii >> 8, k = ii & 255;
        float v = (k < 128) ? dWih1[n * 128 + k] : dWhh1[n * 128 + (k - 128)];
        Wd1[ii] = (short)f2bf(v);
    } else if (i < N0 + N1 + N2 + N3 + 2048) {
        int ii = i - (N0 + N1 + N2 + N3);
        int set = ii >> 9, r = ii & 511, j = r >> 2, q = r & 3;
        int g = q * 128 + j;
        float v = (set == 0) ? ebih0[g] + ebhh0[g]
                : (set == 1) ? ebih1[g] + ebhh1[g]
                : (set == 2) ? dbih0[g] + dbhh0[g]
                             : dbih1[g] + dbhh1[g];
        bsT[ii] = v;
    } else if (i < N0 + N1 + N2 + N3 + 2048 + 1024) {
        int ii = i - (N0 + N1 + N2 + N3 + 2048);
        int j = ii >> 3, e = ii & 7, q = e >> 1, cc = e & 1;
        wyT[ii] = dWih0[(q * 128 + j) * 2 + cc];
    }
}

// ---------------------------------------------------------------------------
// main kernel (per block: 64 batch rows, 8 waves)
// LDS h-buffers ping-pong [2] x (64 rows x 16 chunks): slot = m*16+(kc^(m&15))
// xbuf ping-pong [2] x (64 rows x 4 chunks): slot = m*4+(kc^(m&3))
// c-state in LDS: cbuf[m*132 + j] (2-way bank access = free)
// Wave w: m-tiles {0..3}, n-tiles {w, w+8, w+16, w+24} (q = gate i/f/g/o)
// mma4: b0/b1 prefetched one kk-round ahead (6 B-frags live = 24 regs),
// b2/b3 loaded fresh and covered by the 8 MFMAs on b0/b1.
// ---------------------------------------------------------------------------

template <int NKT>
__device__ __forceinline__ void mma4(float4v acc[4][4], const short8* __restrict__ hb,
                                     const char* __restrict__ wb, const unsigned* wo,
                                     int woff, int nib, int quad)
{
    const char* pb = wb + woff;
    short8 b0 = *(const short8*)(pb + wo[0]);
    short8 b1 = *(const short8*)(pb + wo[1]);
#pragma unroll 1
    for (int kk = 0; kk < NKT; ++kk) {
        int sx = ((kk * 4 + quad) ^ nib) + nib * 16;
        short8 a0 = hb[sx];
        short8 a1 = hb[256 + sx];
        short8 a2 = hb[512 + sx];
        short8 a3 = hb[768 + sx];
        short8 b2 = *(const short8*)(wb + (wo[2] + woff + kk * 64));
        short8 b3 = *(const short8*)(wb + (wo[3] + woff + kk * 64));
        short8 n0 = b0, n1 = b1;
        if (kk + 1 < NKT) {
            const char* pn = wb + woff + (kk + 1) * 64;
            n0 = *(const short8*)(pn + wo[0]);
            n1 = *(const short8*)(pn + wo[1]);
        }
        // consume pre-issued b0/b1 first (arrived ~1 round ago), covering
        // the fresh b2/b3 latency with 8 MFMAs
        acc[0][0] = MFMA16(a0, b0, acc[0][0]);
        acc[0][1] = MFMA16(a1, b0, acc[0][1]);
        acc[0][2] = MFMA16(a2, b0, acc[0][2]);
        acc[0][3] = MFMA16(a3, b0, acc[0][3]);
        acc[1][0] = MFMA16(a0, b1, acc[1][0]);
        acc[1][1] = MFMA16(a1, b1, acc[1][1]);
        acc[1][2] = MFMA16(a2, b1, acc[1][2]);
        acc[1][3] = MFMA16(a3, b1, acc[1][3]);
        acc[2][0] = MFMA16(a0, b2, acc[2][0]);
        acc[2][1] = MFMA16(a1, b2, acc[2][1]);
        acc[2][2] = MFMA16(a2, b2, acc[2][2]);
        acc[2][3] = MFMA16(a3, b2, acc[2][3]);
        acc[3][0] = MFMA16(a0, b3, acc[3][0]);
        acc[3][1] = MFMA16(a1, b3, acc[3][1]);
        acc[3][2] = MFMA16(a2, b3, acc[3][2]);
        acc[3][3] = MFMA16(a3, b3, acc[3][3]);
        b0 = n0; b1 = n1;
    }
}

// elementwise LSTM cell update; c-state in LDS (cbase), h (bf16) to hdst
template <bool DEC0>
__device__ __forceinline__ void cell_update4(float4v acc[4][4], float4v bv,
                                             float* __restrict__ cbase,
                                             unsigned short* __restrict__ hdst,
                                             const float* __restrict__ ybuf,
                                             float4v wy0, float4v wy1,
                                             int j, int quad)
{
    int kc = j >> 3;
    int jl = j & 7;
#pragma unroll
    for (int mt = 0; mt < 4; ++mt) {
#pragma unroll
        for (int r = 0; r < 4; ++r) {
            float gi = acc[0][mt][r] + bv[0];
            float gf = acc[1][mt][r] + bv[1];
            float gg = acc[2][mt][r] + bv[2];
            float go = acc[3][mt][r] + bv[3];
            int m = mt * 16 + quad * 4 + r;
            if (DEC0) {
                float y0 = ybuf[2 * m], y1 = ybuf[2 * m + 1];
                gi += y0 * wy0[0] + y1 * wy0[1];
                gf += y0 * wy0[2] + y1 * wy0[3];
                gg += y0 * wy1[0] + y1 * wy1[1];
                go += y0 * wy1[2] + y1 * wy1[3];
            }
            float si = sigm(gi);
            float sf = sigm(gf);
            float tg = tanh_(gg);
            float so = sigm(go);
            float* cp = cbase + (m * 132 + j);
            float c = sf * (*cp) + si * tg;
            *cp = c;
            float h = so * tanh_(c);
            int slot = m * 16 + (kc ^ (m & 15));
            hdst[slot * 8 + jl] = f2bf(h);
        }
    }
}

__global__ void __attribute__((amdgpu_flat_work_group_size(512, 512), amdgpu_waves_per_eu(2)))
lstm_main(
    const float* __restrict__ hist,
    const float* __restrict__ headW, const float* __restrict__ headB,
    const int* __restrict__ futlen, const void* __restrict__ ws,
    float* __restrict__ out)
{
    __shared__ short8 h0buf[2][1024];  // ping-pong, 64 rows x 16 chunks (32 KB)
    __shared__ short8 h1buf[2][1024];  // 32 KB
    __shared__ short8 xbuf[2][256];    // ping-pong, 64 rows x 4 chunks (8 KB)
    __shared__ float ybuf[128];        // [64][2]
    __shared__ float cbuf0[64 * 132];  // c-state layer 0 (33 KB)
    __shared__ float cbuf1[64 * 132];  // c-state layer 1 (33 KB)

    const char* wsb = (const char*)ws;
    const char* We0 = wsb;                       // rows of 320 B
    const char* We1 = wsb + 512 * 160 * 2;       // rows of 512 B
    const char* Wd0 = We1 + 512 * 256 * 2;       // rows of 256 B
    const char* Wd1 = Wd0 + 512 * 128 * 2;       // rows of 512 B
    const float* bsT = (const float*)(wsb + 819200);
    const float* wyT = bsT + 2048;

    const int tid = threadIdx.x;
    const int w = tid >> 6;
    const int lane = tid & 63;
    const int quad = lane >> 4;
    const int nib = lane & 15;
    const int b0 = blockIdx.x * 64;
    const int TFUT = *futlen;
    const int j = 16 * w + nib;

    // zero-init LDS state. h1: BOTH parities (pipelined L1(0) reads h1[1]).
    // xbuf: both parities, all chunks (chunks 2-3 are permanent K=32 padding).
    h0buf[0][tid] = (short8)0;
    h0buf[0][512 + tid] = (short8)0;
    h1buf[0][tid] = (short8)0;
    h1buf[0][512 + tid] = (short8)0;
    h1buf[1][tid] = (short8)0;
    h1buf[1][512 + tid] = (short8)0;
    ((short8*)xbuf)[tid] = (short8)0;   // 512 slots = both parities
    if (tid < 128) ybuf[tid] = 0.0f;
    for (int i = tid; i < 64 * 132; i += 512) {
        cbuf0[i] = 0.0f;
        cbuf1[i] = 0.0f;
    }
    __syncthreads();  // zero-init visible before initial staging writes

    // stage x(t=0) into xbuf[0]
    if (tid < 128) {
        int m = tid & 63, part = tid >> 6;
        const float* hp = hist + ((size_t)((b0 + m) * 20 + 0)) * 10;
        float v[8];
        if (part == 0) {
#pragma unroll
            for (int i = 0; i < 8; ++i) v[i] = hp[i];
        } else {
            v[0] = hp[8]; v[1] = hp[9];
#pragma unroll
            for (int i = 2; i < 8; ++i) v[i] = 0.0f;
        }
        short8 pk;
#pragma unroll
        for (int i = 0; i < 8; ++i) pk[i] = (short)f2bf(v[i]);
        xbuf[0][m * 4 + (part ^ (m & 3))] = pk;
    }

    // 32-bit B-row byte offsets (per lane): row = 16*(w+8q)+nib, + quad*16
    // eo1 also serves decoder layer 1 (Wd1 has the same 512-B row stride).
    unsigned eo0[4], eo1[4];
#pragma unroll
    for (int q = 0; q < 4; ++q) {
        unsigned row = 16u * (w + 8 * q) + nib;
        eo0[q] = row * 320u + quad * 16u;
        eo1[q] = row * 512u + quad * 16u;
    }
    int p0 = 0, p1 = 0, px = 0;
    __syncthreads();

    // ================= ENCODER: 21 layer-pipelined windows =================
    // window wdw: L0(wdw) [wdw<20] + L1(wdw-1) [wdw>=1]; ONE barrier.
#pragma unroll 1
    for (int wdw = 0; wdw < 21; ++wdw) {
        if (wdw < 20) {
            // ---- L0(wdw): gates = x@Wih0^T + h0@Whh0^T; fused cell ----
            float4v acc[4][4];
#pragma unroll
            for (int q = 0; q < 4; ++q)
#pragma unroll
                for (int mt = 0; mt < 4; ++mt) acc[q][mt] = (float4v){0.f, 0.f, 0.f, 0.f};
            // x part (k 0..31) from xbuf[px]
            {
                const short8* xb = xbuf[px];
                int sxx = (quad ^ (nib & 3)) + nib * 4;
                short8 a0 = xb[sxx];
                short8 a1 = xb[64 + sxx];
                short8 a2 = xb[128 + sxx];
                short8 a3 = xb[192 + sxx];
                short8 bq0 = *(const short8*)(We0 + eo0[0]);
                short8 bq1 = *(const short8*)(We0 + eo0[1]);
                short8 bq2 = *(const short8*)(We0 + eo0[2]);
                short8 bq3 = *(const short8*)(We0 + eo0[3]);
                acc[0][0] = MFMA16(a0, bq0, acc[0][0]);
                acc[0][1] = MFMA16(a1, bq0, acc[0][1]);
                acc[0][2] = MFMA16(a2, bq0, acc[0][2]);
                acc[0][3] = MFMA16(a3, bq0, acc[0][3]);
                acc[1][0] = MFMA16(a0, bq1, acc[1][0]);
                acc[1][1] = MFMA16(a1, bq1, acc[1][1]);
                acc[1][2] = MFMA16(a2, bq1, acc[1][2]);
                acc[1][3] = MFMA16(a3, bq1, acc[1][3]);
                acc[2][0] = MFMA16(a0, bq2, acc[2][0]);
                acc[2][1] = MFMA16(a1, bq2, acc[2][1]);
                acc[2][2] = MFMA16(a2, bq2, acc[2][2]);
                acc[2][3] = MFMA16(a3, bq2, acc[2][3]);
                acc[3][0] = MFMA16(a0, bq3, acc[3][0]);
                acc[3][1] = MFMA16(a1, bq3, acc[3][1]);
                acc[3][2] = MFMA16(a2, bq3, acc[3][2]);
                acc[3][3] = MFMA16(a3, bq3, acc[3][3]);
            }
            // h part (W k 32..159, bytes 64..) from h0buf[p0]
            mma4<4>(acc, h0buf[p0], We0, eo0, 64, nib, quad);
            float4v bv = *(const float4v*)(bsT + 0 * 512 + j * 4);
            cell_update4<false>(acc, bv, cbuf0, (unsigned short*)h0buf[p0 ^ 1], nullptr,
                                (float4v){0, 0, 0, 0}, (float4v){0, 0, 0, 0}, j, quad);
        }

        // stage x(wdw+1) into xbuf[px^1] (consumed next window after barrier)
        if (tid < 128 && wdw < 19) {
            int m = tid & 63, part = tid >> 6;
            const float* hp = hist + ((size_t)((b0 + m) * 20 + (wdw + 1))) * 10;
            float v[8];
            if (part == 0) {
#pragma unroll
                for (int i = 0; i < 8; ++i) v[i] = hp[i];
            } else {
                v[0] = hp[8]; v[1] = hp[9];
#pragma unroll
                for (int i = 2; i < 8; ++i) v[i] = 0.0f;
            }
            short8 pk;
#pragma unroll
            for (int i = 0; i < 8; ++i) pk[i] = (short)f2bf(v[i]);
            xbuf[px ^ 1][m * 4 + (part ^ (m & 3))] = pk;
        }

        if (wdw >= 1) {
            // ---- L1(wdw-1): gates = h0(wdw-1)@Wih1^T + h1(wdw-2)@Whh1^T ----
            float4v acc[4][4];
#pragma unroll
            for (int q = 0; q < 4; ++q)
#pragma unroll
                for (int mt = 0; mt < 4; ++mt) acc[q][mt] = (float4v){0.f, 0.f, 0.f, 0.f};
            mma4<4>(acc, h0buf[p0], We1, eo1, 0, nib, quad);   // pre-window h0
            mma4<4>(acc, h1buf[p1], We1, eo1, 256, nib, quad);
            float4v bv = *(const float4v*)(bsT + 1 * 512 + j * 4);
            cell_update4<false>(acc, bv, cbuf1, (unsigned short*)h1buf[p1 ^ 1], nullptr,
                                (float4v){0, 0, 0, 0}, (float4v){0, 0, 0, 0}, j, quad);
        }
        __syncthreads();
        p0 ^= 1; p1 ^= 1; px ^= 1;
    }

    // Parity ledger: h0(19) -> h0[0]; h1(19) -> h1[1].
    p0 = 0;
    p1 = 1;

    // ================= DECODER =================
    // Per window s: [head(s-1) || mma0(s)] -> A -> cell0(s) -> B ->
    //               mma1(s)+cell1(s) -> C.   Epilogue: head(TFUT-1).
    unsigned do0[4];
#pragma unroll
    for (int q = 0; q < 4; ++q) {
        unsigned row = 16u * (w + 8 * q) + nib;
        do0[q] = row * 256u + quad * 16u;
    }

#pragma unroll 1
    for (int t = 0; t < TFUT; ++t) {
        // ---- head(t-1) (tid<128, hidden behind mma0) ----
        if (tid < 128 && t >= 1) {
            int m = tid & 63, jj = tid >> 6;
            const short8* hb = h1buf[p1];
            const float4v* hw = (const float4v*)(headW + jj * 128);
            float dot = headB[jj];
            int mk = m & 15;
#pragma unroll
            for (int kc = 0; kc < 16; ++kc) {
                short8 ch = hb[m * 16 + (kc ^ mk)];
                float4v w0 = hw[kc * 2], w1 = hw[kc * 2 + 1];
                dot += bf2f((unsigned short)ch[0]) * w0[0];
                dot += bf2f((unsigned short)ch[1]) * w0[1];
                dot += bf2f((unsigned short)ch[2]) * w0[2];
                dot += bf2f((unsigned short)ch[3]) * w0[3];
                dot += bf2f((unsigned short)ch[4]) * w1[0];
                dot += bf2f((unsigned short)ch[5]) * w1[1];
                dot += bf2f((unsigned short)ch[6]) * w1[2];
                dot += bf2f((unsigned short)ch[7]) * w1[3];
            }
            ybuf[2 * m + jj] = dot;
            out[((size_t)(b0 + m) * TFUT + (t - 1)) * 2 + jj] = dot;
        }

        // ---- dec layer 0: mma0 -> A -> cell0 (uses y(t-1)) ----
        {
            float4v acc[4][4];
#pragma unroll
            for (int q = 0; q < 4; ++q)
#pragma unroll
                for (int mt = 0; mt < 4; ++mt) acc[q][mt] = (float4v){0.f, 0.f, 0.f, 0.f};
            mma4<4>(acc, h0buf[p0], Wd0, do0, 0, nib, quad);
            float4v bv = *(const float4v*)(bsT + 2 * 512 + j * 4);
            float4v wy0 = *(const float4v*)(wyT + j * 8);
            float4v wy1 = *(const float4v*)(wyT + j * 8 + 4);
            __syncthreads();  // A: ybuf(t-1) visible
            cell_update4<true>(acc, bv, cbuf0, (unsigned short*)h0buf[p0 ^ 1],
                               ybuf, wy0, wy1, j, quad);
        }
        __syncthreads();  // B: h0 new visible

        // ---- dec layer 1; fused cell ----
        {
            float4v acc[4][4];
#pragma unroll
            for (int q = 0; q < 4; ++q)
#pragma unroll
                for (int mt = 0; mt < 4; ++mt) acc[q][mt] = (float4v){0.f, 0.f, 0.f, 0.f};
            mma4<4>(acc, h0buf[p0 ^ 1], Wd1, eo1, 0, nib, quad);
            mma4<4>(acc, h1buf[p1], Wd1, eo1, 256, nib, quad);
            float4v bv = *(const float4v*)(bsT + 3 * 512 + j * 4);
            cell_update4<false>(acc, bv, cbuf1, (unsigned short*)h1buf[p1 ^ 1], nullptr,
                                (float4v){0, 0, 0, 0}, (float4v){0, 0, 0, 0}, j, quad);
        }
        __syncthreads();  // C: h1 new visible (next window's head reads it)
        p0 ^= 1; p1 ^= 1;
    }

    // ---- epilogue: head(TFUT-1) ----
    if (tid < 128) {
        int m = tid & 63, jj = tid >> 6;
        const short8* hb = h1buf[p1];
        const float4v* hw = (const float4v*)(headW + jj * 128);
        float dot = headB[jj];
        int mk = m & 15;
#pragma unroll
        for (int kc = 0; kc < 16; ++kc) {
            short8 ch = hb[m * 16 + (kc ^ mk)];
            float4v w0 = hw[kc * 2], w1 = hw[kc * 2 + 1];
            dot += bf2f((unsigned short)ch[0]) * w0[0];
            dot += bf2f((unsigned short)ch[1]) * w0[1];
            dot += bf2f((unsigned short)ch[2]) * w0[2];
            dot += bf2f((unsigned short)ch[3]) * w0[3];
            dot += bf2f((unsigned short)ch[4]) * w1[0];
            dot += bf2f((unsigned short)ch[5]) * w1[1];
            dot += bf2f((unsigned short)ch[6]) * w1[2];
            dot += bf2f((unsigned short)ch[7]) * w1[3];
        }
        out[((size_t)(b0 + m) * TFUT + (TFUT - 1)) * 2 + jj] = dot;
    }
}

extern "C" void kernel_launch(void* const* d_in, const int* in_sizes, int n_in,
                              void* d_out, int out_size, void* d_ws, size_t ws_size,
                              hipStream_t stream)
{
    const float* hist   = (const float*)d_in[0];
    const float* eWih0  = (const float*)d_in[1];
    const float* eWhh0  = (const float*)d_in[2];
    const float* ebih0  = (const float*)d_in[3];
    const float* ebhh0  = (const float*)d_in[4];
    const float* eWih1  = (const float*)d_in[5];
    const float* eWhh1  = (const float*)d_in[6];
    const float* ebih1  = (const float*)d_in[7];
    const float* ebhh1  = (const float*)d_in[8];
    const float* dWih0  = (const float*)d_in[9];
    const float* dWhh0  = (const float*)d_in[10];
    const float* dbih0  = (const float*)d_in[11];
    const float* dbhh0  = (const float*)d_in[12];
    const float* dWih1  = (const float*)d_in[13];
    const float* dWhh1  = (const float*)d_in[14];
    const float* dbih1  = (const float*)d_in[15];
    const float* dbhh1  = (const float*)d_in[16];
    const float* headW  = (const float*)d_in[17];
    const float* headB  = (const float*)d_in[18];
    const int*   futlen = (const int*)d_in[19];

    // weights 409600 bf16 + bsT 2048 f32 + wyT 1024 f32 -> 412672 work items
    prep_kernel<<<1612, 256, 0, stream>>>(eWih0, eWhh0, ebih0, ebhh0,
                                          eWih1, eWhh1, ebih1, ebhh1,
                                          dWih0, dWhh0, dbih0, dbhh0,
                                          dWih1, dWhh1, dbih1, dbhh1, d_ws);

    lstm_main<<<256, 512, 0, stream>>>(hist, headW, headB, futlen,
                                       d_ws, (float*)d_out);
}

// Round 15
// 832.575 us; speedup vs baseline: 1.1763x; 1.0345x over previous
//
#include <hip/hip_runtime.h>

// ---------------------------------------------------------------------------
// LSTM forecaster. R15 = R14 + FULL depth-1 b-prefetch at constant register
// budget: all 4 next-round B-frags issued at round start (8 b live = 32r),
// A-frags consumed in 2+2 halves (a-live 8, was 16) -> frag regs 40 = R14's.
// R14's half-prefetch failed (+1.2% only) because each round still blocked
// on the fresh b2/b3 pair -> full L2 latency/round. Now every round waits
// only on 1-round-old loads. Per-acc K-order unchanged -> bit-identical.
// Structure: 256 blocks x 64 batch, 8 waves, 4m x 4n, c-state in LDS,
// encoder layer-pipelined (1 barrier/window), decoder head hoisted.
// ---------------------------------------------------------------------------

typedef __attribute__((ext_vector_type(8))) short short8;   // 8 x bf16 frag
typedef __attribute__((ext_vector_type(4))) float float4v;  // 4 x f32 acc

#define MFMA16(a, b, c) __builtin_amdgcn_mfma_f32_16x16x32_bf16((a), (b), (c), 0, 0, 0)

__device__ __forceinline__ unsigned short f2bf(float x) {
    unsigned u = __builtin_bit_cast(unsigned, x);
    unsigned r = (u + 0x7FFFu + ((u >> 16) & 1u)) >> 16;  // RNE
    return (unsigned short)r;
}
__device__ __forceinline__ float bf2f(unsigned short b) {
    unsigned u = ((unsigned)b) << 16;
    return __builtin_bit_cast(float, u);
}

#if __has_builtin(__builtin_amdgcn_exp2f)
__device__ __forceinline__ float vexp2(float x) { return __builtin_amdgcn_exp2f(x); }
#else
__device__ __forceinline__ float vexp2(float x) { return exp2f(x); }
#endif
#if __has_builtin(__builtin_amdgcn_rcpf)
__device__ __forceinline__ float vrcp(float x) { return __builtin_amdgcn_rcpf(x); }
#else
__device__ __forceinline__ float vrcp(float x) { return 1.0f / x; }
#endif

__device__ __forceinline__ float sigm(float x) {
    return vrcp(1.0f + vexp2(x * -1.442695040888963f));
}
__device__ __forceinline__ float tanh_(float x) {
    return 1.0f - 2.0f * vrcp(1.0f + vexp2(x * 2.885390081777927f));
}

// ---------------------------------------------------------------------------
// prep kernel: fp32 weights -> bf16, concatenated per-layer [Wih | Whh],
// Wih0 padded 10->32; biases summed AND transposed to [set][j][q] float4;
// decoder-y weights transposed to [j][8].
// ws layout: We0[512][160] | We1[512][256] | Wd0[512][128] | Wd1[512][256]
//            (bf16, 819200 B) | bsT[4][128][4] f32 (8 KB) | wyT[128][8] f32 (4 KB)
// ---------------------------------------------------------------------------
__global__ void prep_kernel(const float* __restrict__ eWih0, const float* __restrict__ eWhh0,
                            const float* __restrict__ ebih0, const float* __restrict__ ebhh0,
                            const float* __restrict__ eWih1, const float* __restrict__ eWhh1,
                            const float* __restrict__ ebih1, const float* __restrict__ ebhh1,
                            const float* __restrict__ dWih0, const float* __restrict__ dWhh0,
                            const float* __restrict__ dbih0, const float* __restrict__ dbhh0,
                            const float* __restrict__ dWih1, const float* __restrict__ dWhh1,
                            const float* __restrict__ dbih1, const float* __restrict__ dbhh1,
                            void* __restrict__ ws)
{
    int i = blockIdx.x * 256 + threadIdx.x;
    short* We0 = (short*)ws;
    short* We1 = We0 + 512 * 160;
    short* Wd0 = We1 + 512 * 256;
    short* Wd1 = Wd0 + 512 * 128;
    float* bsT = (float*)((char*)ws + 819200);
    float* wyT = bsT + 2048;
    const int N0 = 512 * 160, N1 = 512 * 256, N2 = 512 * 128, N3 = 512 * 256;
    if (i < N0) {
        int n = i / 160, k = i - n * 160;
        float v = (k < 32) ? (k < 10 ? eWih0[n * 10 + k] : 0.0f) : eWhh0[n * 128 + (k - 32)];
        We0[i] = (short)f2bf(v);
    } else if (i < N0 + N1) {
        int ii = i - N0, n = ii >> 8, k = ii & 255;
        float v = (k < 128) ? eWih1[n * 128 + k] : eWhh1[n * 128 + (k - 128)];
        We1[ii] = (short)f2bf(v);
    } else if (i < N0 + N1 + N2) {
        int ii = i - (N0 + N1);
        Wd0[ii] = (short)f2bf(dWhh0[ii]);
    } else if (i < N0 + N1 + N2 + N3) {
        int ii = i - (N0 + N1 + N2), n = ii >> 8, k = ii & 255;
        float v = (k < 128) ? dWih1[n * 128 + k] : dWhh1[n * 128 + (k - 128)];
        Wd1[ii] = (short)f2bf(v);
    } else if (i < N0 + N1 + N2 + N3 + 2048) {
        int ii = i - (N0 + N1 + N2 + N3);
        int set = ii >> 9, r = ii & 511, j = r >> 2, q = r & 3;
        int g = q * 128 + j;
        float v = (set == 0) ? ebih0[g] + ebhh0[g]
                : (set == 1) ? ebih1[g] + ebhh1[g]
                : (set == 2) ? dbih0[g] + dbhh0[g]
                             : dbih1[g] + dbhh1[g];
        bsT[ii] = v;
    } else if (i < N0 + N1 + N2 + N3 + 2048 + 1024) {
        int ii = i - (N0 + N1 + N2 + N3 + 2048);
        int j = ii >> 3, e = ii & 7, q = e >> 1, cc = e & 1;
        wyT[ii] = dWih0[(q * 128 + j) * 2 + cc];
    }
}

// ---------------------------------------------------------------------------
// main kernel (per block: 64 batch rows, 8 waves)
// LDS h-buffers ping-pong [2] x (64 rows x 16 chunks): slot = m*16+(kc^(m&15))
// xbuf ping-pong [2] x (64 rows x 4 chunks): slot = m*4+(kc^(m&3))
// c-state in LDS: cbuf[m*132 + j] (2-way bank access = free)
// Wave w: m-tiles {0..3}, n-tiles {w, w+8, w+16, w+24} (q = gate i/f/g/o)
// mma4: full depth-1 b-prefetch (8 b-frags live); a consumed in 2+2 halves.
// ---------------------------------------------------------------------------

template <int NKT>
__device__ __forceinline__ void mma4(float4v acc[4][4], const short8* __restrict__ hb,
                                     const char* __restrict__ wb, const unsigned* wo,
                                     int woff, int nib, int quad)
{
    const char* pb = wb + woff;
    short8 b0 = *(const short8*)(pb + wo[0]);
    short8 b1 = *(const short8*)(pb + wo[1]);
    short8 b2 = *(const short8*)(pb + wo[2]);
    short8 b3 = *(const short8*)(pb + wo[3]);
#pragma unroll 1
    for (int kk = 0; kk < NKT; ++kk) {
        // issue next round's 4 b-loads FIRST (independent of this round)
        short8 n0 = b0, n1 = b1, n2 = b2, n3 = b3;
        if (kk + 1 < NKT) {
            const char* pn = wb + woff + (kk + 1) * 64;
            n0 = *(const short8*)(pn + wo[0]);
            n1 = *(const short8*)(pn + wo[1]);
            n2 = *(const short8*)(pn + wo[2]);
            n3 = *(const short8*)(pn + wo[3]);
        }
        int sx = ((kk * 4 + quad) ^ nib) + nib * 16;
        // first a-half: a0,a1 (a-live 2 frags)
        short8 a0 = hb[sx];
        short8 a1 = hb[256 + sx];
        acc[0][0] = MFMA16(a0, b0, acc[0][0]);
        acc[0][1] = MFMA16(a1, b0, acc[0][1]);
        acc[1][0] = MFMA16(a0, b1, acc[1][0]);
        acc[1][1] = MFMA16(a1, b1, acc[1][1]);
        acc[2][0] = MFMA16(a0, b2, acc[2][0]);
        acc[2][1] = MFMA16(a1, b2, acc[2][1]);
        acc[3][0] = MFMA16(a0, b3, acc[3][0]);
        acc[3][1] = MFMA16(a1, b3, acc[3][1]);
        // second a-half: a2,a3
        short8 a2 = hb[512 + sx];
        short8 a3 = hb[768 + sx];
        acc[0][2] = MFMA16(a2, b0, acc[0][2]);
        acc[0][3] = MFMA16(a3, b0, acc[0][3]);
        acc[1][2] = MFMA16(a2, b1, acc[1][2]);
        acc[1][3] = MFMA16(a3, b1, acc[1][3]);
        acc[2][2] = MFMA16(a2, b2, acc[2][2]);
        acc[2][3] = MFMA16(a3, b2, acc[2][3]);
        acc[3][2] = MFMA16(a2, b3, acc[3][2]);
        acc[3][3] = MFMA16(a3, b3, acc[3][3]);
        b0 = n0; b1 = n1; b2 = n2; b3 = n3;
    }
}

// elementwise LSTM cell update; c-state in LDS (cbase), h (bf16) to hdst
template <bool DEC0>
__device__ __forceinline__ void cell_update4(float4v acc[4][4], float4v bv,
                                             float* __restrict__ cbase,
                                             unsigned short* __restrict__ hdst,
                                             const float* __restrict__ ybuf,
                                             float4v wy0, float4v wy1,
                                             int j, int quad)
{
    int kc = j >> 3;
    int jl = j & 7;
#pragma unroll
    for (int mt = 0; mt < 4; ++mt) {
#pragma unroll
        for (int r = 0; r < 4; ++r) {
            float gi = acc[0][mt][r] + bv[0];
            float gf = acc[1][mt][r] + bv[1];
            float gg = acc[2][mt][r] + bv[2];
            float go = acc[3][mt][r] + bv[3];
            int m = mt * 16 + quad * 4 + r;
            if (DEC0) {
                float y0 = ybuf[2 * m], y1 = ybuf[2 * m + 1];
                gi += y0 * wy0[0] + y1 * wy0[1];
                gf += y0 * wy0[2] + y1 * wy0[3];
                gg += y0 * wy1[0] + y1 * wy1[1];
                go += y0 * wy1[2] + y1 * wy1[3];
            }
            float si = sigm(gi);
            float sf = sigm(gf);
            float tg = tanh_(gg);
            float so = sigm(go);
            float* cp = cbase + (m * 132 + j);
            float c = sf * (*cp) + si * tg;
            *cp = c;
            float h = so * tanh_(c);
            int slot = m * 16 + (kc ^ (m & 15));
            hdst[slot * 8 + jl] = f2bf(h);
        }
    }
}

__global__ void __attribute__((amdgpu_flat_work_group_size(512, 512), amdgpu_waves_per_eu(2)))
lstm_main(
    const float* __restrict__ hist,
    const float* __restrict__ headW, const float* __restrict__ headB,
    const int* __restrict__ futlen, const void* __restrict__ ws,
    float* __restrict__ out)
{
    __shared__ short8 h0buf[2][1024];  // ping-pong, 64 rows x 16 chunks (32 KB)
    __shared__ short8 h1buf[2][1024];  // 32 KB
    __shared__ short8 xbuf[2][256];    // ping-pong, 64 rows x 4 chunks (8 KB)
    __shared__ float ybuf[128];        // [64][2]
    __shared__ float cbuf0[64 * 132];  // c-state layer 0 (33 KB)
    __shared__ float cbuf1[64 * 132];  // c-state layer 1 (33 KB)

    const char* wsb = (const char*)ws;
    const char* We0 = wsb;                       // rows of 320 B
    const char* We1 = wsb + 512 * 160 * 2;       // rows of 512 B
    const char* Wd0 = We1 + 512 * 256 * 2;       // rows of 256 B
    const char* Wd1 = Wd0 + 512 * 128 * 2;       // rows of 512 B
    const float* bsT = (const float*)(wsb + 819200);
    const float* wyT = bsT + 2048;

    const int tid = threadIdx.x;
    const int w = tid >> 6;
    const int lane = tid & 63;
    const int quad = lane >> 4;
    const int nib = lane & 15;
    const int b0 = blockIdx.x * 64;
    const int TFUT = *futlen;
    const int j = 16 * w + nib;

    // zero-init LDS state. h1: BOTH parities (pipelined L1(0) reads h1[1]).
    // xbuf: both parities, all chunks (chunks 2-3 are permanent K=32 padding).
    h0buf[0][tid] = (short8)0;
    h0buf[0][512 + tid] = (short8)0;
    h1buf[0][tid] = (short8)0;
    h1buf[0][512 + tid] = (short8)0;
    h1buf[1][tid] = (short8)0;
    h1buf[1][512 + tid] = (short8)0;
    ((short8*)xbuf)[tid] = (short8)0;   // 512 slots = both parities
    if (tid < 128) ybuf[tid] = 0.0f;
    for (int i = tid; i < 64 * 132; i += 512) {
        cbuf0[i] = 0.0f;
        cbuf1[i] = 0.0f;
    }
    __syncthreads();  // zero-init visible before initial staging writes

    // stage x(t=0) into xbuf[0]
    if (tid < 128) {
        int m = tid & 63, part = tid >> 6;
        const float* hp = hist + ((size_t)((b0 + m) * 20 + 0)) * 10;
        float v[8];
        if (part == 0) {
#pragma unroll
            for (int i = 0; i < 8; ++i) v[i] = hp[i];
        } else {
            v[0] = hp[8]; v[1] = hp[9];
#pragma unroll
            for (int i = 2; i < 8; ++i) v[i] = 0.0f;
        }
        short8 pk;
#pragma unroll
        for (int i = 0; i < 8; ++i) pk[i] = (short)f2bf(v[i]);
        xbuf[0][m * 4 + (part ^ (m & 3))] = pk;
    }

    // 32-bit B-row byte offsets (per lane): row = 16*(w+8q)+nib, + quad*16
    // eo1 also serves decoder layer 1 (Wd1 has the same 512-B row stride).
    unsigned eo0[4], eo1[4];
#pragma unroll
    for (int q = 0; q < 4; ++q) {
        unsigned row = 16u * (w + 8 * q) + nib;
        eo0[q] = row * 320u + quad * 16u;
        eo1[q] = row * 512u + quad * 16u;
    }
    int p0 = 0, p1 = 0, px = 0;
    __syncthreads();

    // ================= ENCODER: 21 layer-pipelined windows =================
    // window wdw: L0(wdw) [wdw<20] + L1(wdw-1) [wdw>=1]; ONE barrier.
#pragma unroll 1
    for (int wdw = 0; wdw < 21; ++wdw) {
        if (wdw < 20) {
            // ---- L0(wdw): gates = x@Wih0^T + h0@Whh0^T; fused cell ----
            float4v acc[4][4];
#pragma unroll
            for (int q = 0; q < 4; ++q)
#pragma unroll
                for (int mt = 0; mt < 4; ++mt) acc[q][mt] = (float4v){0.f, 0.f, 0.f, 0.f};
            // x part (k 0..31) from xbuf[px]
            {
                const short8* xb = xbuf[px];
                int sxx = (quad ^ (nib & 3)) + nib * 4;
                short8 a0 = xb[sxx];
                short8 a1 = xb[64 + sxx];
                short8 a2 = xb[128 + sxx];
                short8 a3 = xb[192 + sxx];
                short8 bq0 = *(const short8*)(We0 + eo0[0]);
                short8 bq1 = *(const short8*)(We0 + eo0[1]);
                short8 bq2 = *(const short8*)(We0 + eo0[2]);
                short8 bq3 = *(const short8*)(We0 + eo0[3]);
                acc[0][0] = MFMA16(a0, bq0, acc[0][0]);
                acc[0][1] = MFMA16(a1, bq0, acc[0][1]);
                acc[0][2] = MFMA16(a2, bq0, acc[0][2]);
                acc[0][3] = MFMA16(a3, bq0, acc[0][3]);
                acc[1][0] = MFMA16(a0, bq1, acc[1][0]);
                acc[1][1] = MFMA16(a1, bq1, acc[1][1]);
                acc[1][2] = MFMA16(a2, bq1, acc[1][2]);
                acc[1][3] = MFMA16(a3, bq1, acc[1][3]);
                acc[2][0] = MFMA16(a0, bq2, acc[2][0]);
                acc[2][1] = MFMA16(a1, bq2, acc[2][1]);
                acc[2][2] = MFMA16(a2, bq2, acc[2][2]);
                acc[2][3] = MFMA16(a3, bq2, acc[2][3]);
                acc[3][0] = MFMA16(a0, bq3, acc[3][0]);
                acc[3][1] = MFMA16(a1, bq3, acc[3][1]);
                acc[3][2] = MFMA16(a2, bq3, acc[3][2]);
                acc[3][3] = MFMA16(a3, bq3, acc[3][3]);
            }
            // h part (W k 32..159, bytes 64..) from h0buf[p0]
            mma4<4>(acc, h0buf[p0], We0, eo0, 64, nib, quad);
            float4v bv = *(const float4v*)(bsT + 0 * 512 + j * 4);
            cell_update4<false>(acc, bv, cbuf0, (unsigned short*)h0buf[p0 ^ 1], nullptr,
                                (float4v){0, 0, 0, 0}, (float4v){0, 0, 0, 0}, j, quad);
        }

        // stage x(wdw+1) into xbuf[px^1] (consumed next window after barrier)
        if (tid < 128 && wdw < 19) {
            int m = tid & 63, part = tid >> 6;
            const float* hp = hist + ((size_t)((b0 + m) * 20 + (wdw + 1))) * 10;
            float v[8];
            if (part == 0) {
#pragma unroll
                for (int i = 0; i < 8; ++i) v[i] = hp[i];
            } else {
                v[0] = hp[8]; v[1] = hp[9];
#pragma unroll
                for (int i = 2; i < 8; ++i) v[i] = 0.0f;
            }
            short8 pk;
#pragma unroll
            for (int i = 0; i < 8; ++i) pk[i] = (short)f2bf(v[i]);
            xbuf[px ^ 1][m * 4 + (part ^ (m & 3))] = pk;
        }

        if (wdw >= 1) {
            // ---- L1(wdw-1): gates = h0(wdw-1)@Wih1^T + h1(wdw-2)@Whh1^T ----
            float4v acc[4][4];
#pragma unroll
            for (int q = 0; q < 4; ++q)
#pragma unroll
                for (int mt = 0; mt < 4; ++mt) acc[q][mt] = (float4v){0.f, 0.f, 0.f, 0.f};
            mma4<4>(acc, h0buf[p0], We1, eo1, 0, nib, quad);   // pre-window h0
            mma4<4>(acc, h1buf[p1], We1, eo1, 256, nib, quad);
            float4v bv = *(const float4v*)(bsT + 1 * 512 + j * 4);
            cell_update4<false>(acc, bv, cbuf1, (unsigned short*)h1buf[p1 ^ 1], nullptr,
                                (float4v){0, 0, 0, 0}, (float4v){0, 0, 0, 0}, j, quad);
        }
        __syncthreads();
        p0 ^= 1; p1 ^= 1; px ^= 1;
    }

    // Parity ledger: h0(19) -> h0[0]; h1(19) -> h1[1].
    p0 = 0;
    p1 = 1;

    // ================= DECODER =================
    // Per window s: [head(s-1) || mma0(s)] -> A -> cell0(s) -> B ->
    //               mma1(s)+cell1(s) -> C.   Epilogue: head(TFUT-1).
    unsigned do0[4];
#pragma unroll
    for (int q = 0; q < 4; ++q) {
        unsigned row = 16u * (w + 8 * q) + nib;
        do0[q] = row * 256u + quad * 16u;
    }

#pragma unroll 1
    for (int t = 0; t < TFUT; ++t) {
        // ---- head(t-1) (tid<128, hidden behind mma0) ----
        if (tid < 128 && t >= 1) {
            int m = tid & 63, jj = tid >> 6;
            const short8* hb = h1buf[p1];
            const float4v* hw = (const float4v*)(headW + jj * 128);
            float dot = headB[jj];
            int mk = m & 15;
#pragma unroll
            for (int kc = 0; kc < 16; ++kc) {
                short8 ch = hb[m * 16 + (kc ^ mk)];
                float4v w0 = hw[kc * 2], w1 = hw[kc * 2 + 1];
                dot += bf2f((unsigned short)ch[0]) * w0[0];
                dot += bf2f((unsigned short)ch[1]) * w0[1];
                dot += bf2f((unsigned short)ch[2]) * w0[2];
                dot += bf2f((unsigned short)ch[3]) * w0[3];
                dot += bf2f((unsigned short)ch[4]) * w1[0];
                dot += bf2f((unsigned short)ch[5]) * w1[1];
                dot += bf2f((unsigned short)ch[6]) * w1[2];
                dot += bf2f((unsigned short)ch[7]) * w1[3];
            }
            ybuf[2 * m + jj] = dot;
            out[((size_t)(b0 + m) * TFUT + (t - 1)) * 2 + jj] = dot;
        }

        // ---- dec layer 0: mma0 -> A -> cell0 (uses y(t-1)) ----
        {
            float4v acc[4][4];
#pragma unroll
            for (int q = 0; q < 4; ++q)
#pragma unroll
                for (int mt = 0; mt < 4; ++mt) acc[q][mt] = (float4v){0.f, 0.f, 0.f, 0.f};
            mma4<4>(acc, h0buf[p0], Wd0, do0, 0, nib, quad);
            float4v bv = *(const float4v*)(bsT + 2 * 512 + j * 4);
            float4v wy0 = *(const float4v*)(wyT + j * 8);
            float4v wy1 = *(const float4v*)(wyT + j * 8 + 4);
            __syncthreads();  // A: ybuf(t-1) visible
            cell_update4<true>(acc, bv, cbuf0, (unsigned short*)h0buf[p0 ^ 1],
                               ybuf, wy0, wy1, j, quad);
        }
        __syncthreads();  // B: h0 new visible

        // ---- dec layer 1; fused cell ----
        {
            float4v acc[4][4];
#pragma unroll
            for (int q = 0; q < 4; ++q)
#pragma unroll
                for (int mt = 0; mt < 4; ++mt) acc[q][mt] = (float4v){0.f, 0.f, 0.f, 0.f};
            mma4<4>(acc, h0buf[p0 ^ 1], Wd1, eo1, 0, nib, quad);
            mma4<4>(acc, h1buf[p1], Wd1, eo1, 256, nib, quad);
            float4v bv = *(const float4v*)(bsT + 3 * 512 + j * 4);
            cell_update4<false>(acc, bv, cbuf1, (unsigned short*)h1buf[p1 ^ 1], nullptr,
                                (float4v){0, 0, 0, 0}, (float4v){0, 0, 0, 0}, j, quad);
        }
        __syncthreads();  // C: h1 new visible (next window's head reads it)
        p0 ^= 1; p1 ^= 1;
    }

    // ---- epilogue: head(TFUT-1) ----
    if (tid < 128) {
        int m = tid & 63, jj = tid >> 6;
        const short8* hb = h1buf[p1];
        const float4v* hw = (const float4v*)(headW + jj * 128);
        float dot = headB[jj];
        int mk = m & 15;
#pragma unroll
        for (int kc = 0; kc < 16; ++kc) {
            short8 ch = hb[m * 16 + (kc ^ mk)];
            float4v w0 = hw[kc * 2], w1 = hw[kc * 2 + 1];
            dot += bf2f((unsigned short)ch[0]) * w0[0];
            dot += bf2f((unsigned short)ch[1]) * w0[1];
            dot += bf2f((unsigned short)ch[2]) * w0[2];
            dot += bf2f((unsigned short)ch[3]) * w0[3];
            dot += bf2f((unsigned short)ch[4]) * w1[0];
            dot += bf2f((unsigned short)ch[5]) * w1[1];
            dot += bf2f((unsigned short)ch[6]) * w1[2];
            dot += bf2f((unsigned short)ch[7]) * w1[3];
        }
        out[((size_t)(b0 + m) * TFUT + (TFUT - 1)) * 2 + jj] = dot;
    }
}

extern "C" void kernel_launch(void* const* d_in, const int* in_sizes, int n_in,
                              void* d_out, int out_size, void* d_ws, size_t ws_size,
                              hipStream_t stream)
{
    const float* hist   = (const float*)d_in[0];
    const float* eWih0  = (const float*)d_in[1];
    const float* eWhh0  = (const float*)d_in[2];
    const float* ebih0  = (const float*)d_in[3];
    const float* ebhh0  = (const float*)d_in[4];
    const float* eWih1  = (const float*)d_in[5];
    const float* eWhh1  = (const float*)d_in[6];
    const float* ebih1  = (const float*)d_in[7];
    const float* ebhh1  = (const float*)d_in[8];
    const float* dWih0  = (const float*)d_in[9];
    const float* dWhh0  = (const float*)d_in[10];
    const float* dbih0  = (const float*)d_in[11];
    const float* dbhh0  = (const float*)d_in[12];
    const float* dWih1  = (const float*)d_in[13];
    const float* dWhh1  = (const float*)d_in[14];
    const float* dbih1  = (const float*)d_in[15];
    const float* dbhh1  = (const float*)d_in[16];
    const float* headW  = (const float*)d_in[17];
    const float* headB  = (const float*)d_in[18];
    const int*   futlen = (const int*)d_in[19];

    // weights 409600 bf16 + bsT 2048 f32 + wyT 1024 f32 -> 412672 work items
    prep_kernel<<<1612, 256, 0, stream>>>(eWih0, eWhh0, ebih0, ebhh0,
                                          eWih1, eWhh1, ebih1, ebhh1,
                                          dWih0, dWhh0, dbih0, dbhh0,
                                          dWih1, dWhh1, dbih1, dbhh1, d_ws);

    lstm_main<<<256, 512, 0, stream>>>(hist, headW, headB, futlen,
                                       d_ws, (float*)d_out);
}